// Round 4
// baseline (218.950 us; speedup 1.0000x reference)
//
#include <hip/hip_runtime.h>

#define N_TOK 9216
#define C_DIM 64
#define I_DIM 32
#define BOT 16
#define B_SZ 2
#define N_TILES 144  // N_TOK / 64

typedef short bf16x8 __attribute__((ext_vector_type(8)));
typedef float f32x4 __attribute__((ext_vector_type(4)));
typedef float f32x16 __attribute__((ext_vector_type(16)));

// pack two f32 -> two bf16 (truncation) in one v_perm_b32
__device__ __forceinline__ unsigned packbf(float a, float b) {
  return __builtin_amdgcn_perm(__float_as_uint(b), __float_as_uint(a), 0x07060302u);
}
__device__ __forceinline__ unsigned short bftrunc(float f) {
  return (unsigned short)(__float_as_uint(f) >> 16);
}

// ---------------- fused projections (MFMA 16x16x32) + pooling ----------------
// blocks 0..863: proj wave-tasks (mat, b, 16-token tile).
//   mat0=theta (pre-scaled log2e/T), mat1=phi, mat2=g.
//   Q/K: [B][N][32] bf16 row-major. VT: [B][32][N] bf16.
// blocks 864..991: pooled[bc] = mean_n x[bc][n]
__global__ __launch_bounds__(256) void proj_pool_kernel(
    const float* __restrict__ x, const float* __restrict__ g_w,
    const float* __restrict__ theta_w, const float* __restrict__ phi_w,
    unsigned short* __restrict__ Q, unsigned short* __restrict__ K,
    unsigned short* __restrict__ VT, float* __restrict__ pooled) {
  if (blockIdx.x >= 864) {  // ---- pooling path ----
    int bc = blockIdx.x - 864;  // b*64 + c
    const float* p = x + (size_t)bc * N_TOK;
    float s = 0.f;
    for (int t = threadIdx.x; t < N_TOK; t += 256) s += p[t];
#pragma unroll
    for (int off = 32; off >= 1; off >>= 1) s += __shfl_down(s, off, 64);
    __shared__ float red[4];
    int wid = threadIdx.x >> 6, lane = threadIdx.x & 63;
    if (lane == 0) red[wid] = s;
    __syncthreads();
    if (threadIdx.x == 0)
      pooled[bc] = (red[0] + red[1] + red[2] + red[3]) * (1.0f / N_TOK);
    return;
  }
  const int lane = threadIdx.x & 63;
  const int m = lane & 15, quad = lane >> 4;
  int task = blockIdx.x * 4 + (threadIdx.x >> 6);  // 0..3455
  int mat = task / 1152;
  int r0 = task % 1152;
  int b = r0 / 576;
  int n0 = (r0 % 576) * 16;
  const float* wsrc = (mat == 0) ? theta_w : ((mat == 1) ? phi_w : g_w);
  const float scale = (mat == 0) ? 0.96179669439f : 1.0f;  // log2(e)/1.5

  bf16x8 afr[2][2];  // [itile][cstep] of W
#pragma unroll
  for (int it = 0; it < 2; ++it)
#pragma unroll
    for (int cs = 0; cs < 2; ++cs) {
      const float* wp = wsrc + (it * 16 + m) * C_DIM + cs * 32 + quad * 8;
      union { unsigned u[4]; bf16x8 v; } t;
#pragma unroll
      for (int j = 0; j < 4; ++j)
        t.u[j] = packbf(wp[2 * j] * scale, wp[2 * j + 1] * scale);
      afr[it][cs] = t.v;
    }

  const float* xb = x + (size_t)b * C_DIM * N_TOK + n0 + m;
  bf16x8 bfr[2];
#pragma unroll
  for (int cs = 0; cs < 2; ++cs) {
    union { unsigned u[4]; bf16x8 v; } t;
#pragma unroll
    for (int j = 0; j < 4; ++j) {
      float v0 = xb[(size_t)(cs * 32 + quad * 8 + 2 * j) * N_TOK];
      float v1 = xb[(size_t)(cs * 32 + quad * 8 + 2 * j + 1) * N_TOK];
      t.u[j] = packbf(v0, v1);
    }
    bfr[cs] = t.v;
  }

  f32x4 acc[2] = {{0.f, 0.f, 0.f, 0.f}, {0.f, 0.f, 0.f, 0.f}};
#pragma unroll
  for (int cs = 0; cs < 2; ++cs)
#pragma unroll
    for (int it = 0; it < 2; ++it)
      acc[it] = __builtin_amdgcn_mfma_f32_16x16x32_bf16(afr[it][cs], bfr[cs],
                                                        acc[it], 0, 0, 0);
  // C layout: col(n)=lane&15, row(i)=quad*4+r
  if (mat < 2) {
    unsigned short* dst =
        ((mat == 0) ? Q : K) + ((size_t)b * N_TOK + n0 + m) * I_DIM;
#pragma unroll
    for (int it = 0; it < 2; ++it) {
      unsigned u0 = packbf(acc[it][0], acc[it][1]);
      unsigned u1 = packbf(acc[it][2], acc[it][3]);
      *(uint2*)(dst + it * 16 + quad * 4) = make_uint2(u0, u1);
    }
  } else {
#pragma unroll
    for (int it = 0; it < 2; ++it)
#pragma unroll
      for (int r = 0; r < 4; ++r)
        VT[((size_t)b * I_DIM + it * 16 + quad * 4 + r) * N_TOK + n0 + m] =
            bftrunc(acc[it][r]);
  }
}

// ---------------- flash attention, S^T form, per-wave LDS transpose, no barriers ----------------
// S^T = K@Q^T via 32x32x16 (D: col q=lane&31, row kv=(reg&3)+8*(reg>>2)+4*(lane>>5)).
// P^T packed to bf16, written as ds_write_b64 into per-wave Pw[q][kv] (stride 68),
// read back as A-fragments (ds_read_b64 pairs). No shuffles, no __syncthreads.
// Ypart layout TRANSPOSED: [KS][B][32 i][N q] so stores are dwordx4.
__global__ __launch_bounds__(256, 8) void attn_kernel(
    const unsigned short* __restrict__ Q, const unsigned short* __restrict__ Kg,
    const unsigned short* __restrict__ VT, float* __restrict__ Ypart,
    float* __restrict__ Lpart, int tps) {
  const int lane = threadIdx.x & 63;
  const int l32 = lane & 31, h = lane >> 5;
  const int wid = threadIdx.x >> 6;
  const int qw = blockIdx.x * 4 + wid;
  const int ks = blockIdx.y, b = blockIdx.z;
  const int q0 = qw * 32;
  const unsigned short* Qb = Q + (size_t)b * N_TOK * I_DIM;
  const unsigned short* Kb = Kg + (size_t)b * N_TOK * I_DIM;
  const unsigned short* Vb = VT + (size_t)b * I_DIM * N_TOK;

  __shared__ __align__(16) unsigned short Pw[4][32][68];
  unsigned short(*P)[68] = Pw[wid];

  // Q as B-operand: B[k=c][n=q], lane holds q=l32, c=8h+j
  bf16x8 bq0 = *(const bf16x8*)(Qb + (size_t)(q0 + l32) * I_DIM + h * 8);
  bf16x8 bq1 = *(const bf16x8*)(Qb + (size_t)(q0 + l32) * I_DIM + 16 + h * 8);

  const f32x16 zz = {};
  f32x16 accy = {};
  float lsum = 0.f;

  const int kt0 = ks * tps;
  for (int kt = kt0; kt < kt0 + tps; ++kt) {
    const int k0 = kt * 64;
    const unsigned short* kp = Kb + (size_t)(k0 + l32) * I_DIM + h * 8;
    bf16x8 ak00 = *(const bf16x8*)(kp);
    bf16x8 ak01 = *(const bf16x8*)(kp + 16);
    bf16x8 ak10 = *(const bf16x8*)(kp + 32 * I_DIM);
    bf16x8 ak11 = *(const bf16x8*)(kp + 32 * I_DIM + 16);
    const unsigned short* vp = Vb + (size_t)l32 * N_TOK + k0 + h * 8;
    bf16x8 bv[4];
    bv[0] = *(const bf16x8*)(vp);
    bv[1] = *(const bf16x8*)(vp + 16);
    bv[2] = *(const bf16x8*)(vp + 32);
    bv[3] = *(const bf16x8*)(vp + 48);

    // S^T tiles (kv 0-31 and 32-63)
    f32x16 s0 = __builtin_amdgcn_mfma_f32_32x32x16_bf16(ak00, bq0, zz, 0, 0, 0);
    s0 = __builtin_amdgcn_mfma_f32_32x32x16_bf16(ak01, bq1, s0, 0, 0, 0);
    f32x16 s1 = __builtin_amdgcn_mfma_f32_32x32x16_bf16(ak10, bq0, zz, 0, 0, 0);
    s1 = __builtin_amdgcn_mfma_f32_32x32x16_bf16(ak11, bq1, s1, 0, 0, 0);

    // P = exp2(S) (scale folded into Q); pack; write per-wave LDS rows
    float2 ls2 = make_float2(0.f, 0.f);
#pragma unroll
    for (int t = 0; t < 2; ++t) {
      const f32x16 sv = t ? s1 : s0;
      float e[16];
#pragma unroll
      for (int r = 0; r < 16; ++r) e[r] = __builtin_amdgcn_exp2f(sv[r]);
#pragma unroll
      for (int r = 0; r < 8; ++r) {
        ls2.x += e[2 * r];
        ls2.y += e[2 * r + 1];
      }
      unsigned pk[8];
#pragma unroll
      for (int i = 0; i < 8; ++i) pk[i] = packbf(e[2 * i], e[2 * i + 1]);
      // reg pairs (2i,2i+1) are kv {0..3},{8..11},{16..19},{24..27} (+4h, +32t)
      unsigned short* row = &P[l32][t * 32 + 4 * h];
      *(uint2*)(row) = make_uint2(pk[0], pk[1]);
      *(uint2*)(row + 8) = make_uint2(pk[2], pk[3]);
      *(uint2*)(row + 16) = make_uint2(pk[4], pk[5]);
      *(uint2*)(row + 24) = make_uint2(pk[6], pk[7]);
    }
    lsum += ls2.x + ls2.y;

    // Y += P@V: A-fragment = P[q=l32][kv=16s+8h..+7]
#pragma unroll
    for (int s = 0; s < 4; ++s) {
      union { uint2 d[2]; bf16x8 v; } ap;
      const unsigned short* rp = &P[l32][16 * s + 8 * h];
      ap.d[0] = *(const uint2*)(rp);
      ap.d[1] = *(const uint2*)(rp + 4);
      accy = __builtin_amdgcn_mfma_f32_32x32x16_bf16(ap.v, bv[s], accy, 0, 0, 0);
    }
  }

  lsum += __shfl_xor(lsum, 32, 64);

  // accy: D[q][i], col i = l32, row q = (reg&3)+8*(reg>>2)+4h.
  // Transposed store: Ypart[(ksb)*32+i][q0+8R+4h .. +3] as float4.
  const size_t ib = ((size_t)(ks * B_SZ + b) * I_DIM + l32) * N_TOK + q0 + 4 * h;
#pragma unroll
  for (int R = 0; R < 4; ++R) {
    float4 v = make_float4(accy[4 * R], accy[4 * R + 1], accy[4 * R + 2],
                           accy[4 * R + 3]);
    *(float4*)(Ypart + ib + 8 * R) = v;
  }
  if (h == 0) Lpart[(size_t)(ks * B_SZ + b) * N_TOK + q0 + l32] = lsum;
}

// ---------------- epilogue: gate + reduce partials + GEMV + residual ----------------
__global__ __launch_bounds__(256) void epilogue_kernel(
    const float* __restrict__ x, const float* __restrict__ W_w,
    const float* __restrict__ pooled, const float* __restrict__ cg1_w,
    const float* __restrict__ cg1_b, const float* __restrict__ cg2_w,
    const float* __restrict__ cg2_b, const float* __restrict__ Ypart,
    const float* __restrict__ Lpart, float* __restrict__ out, int KS) {
  __shared__ float Ysh[64][33];
  __shared__ float lsh[64];
  __shared__ float gsh[64];
  __shared__ float hl[BOT];
  const int t = threadIdx.x;
  const int b = blockIdx.y;
  const int n0 = blockIdx.x * 64;

  // gate stage 1: hl = relu(cg1 @ pooled + cg1_b)
  if (t < BOT) {
    float a = cg1_b[t];
#pragma unroll
    for (int c = 0; c < C_DIM; ++c)
      a += cg1_w[t * C_DIM + c] * pooled[b * C_DIM + c];
    hl[t] = a > 0.f ? a : 0.f;
  }

  {  // phase 1: reduce Ypart (layout [KS][B][32 i][N q]) over KS into Ysh[n][i]
    int i = t >> 3, ns = (t & 7) * 8;
    float4 a0 = make_float4(0.f, 0.f, 0.f, 0.f), a1 = a0;
    for (int ks = 0; ks < KS; ++ks) {
      const float* yp =
          Ypart + ((size_t)(ks * B_SZ + b) * I_DIM + i) * N_TOK + n0 + ns;
      float4 v0 = *(const float4*)(yp);
      float4 v1 = *(const float4*)(yp + 4);
      a0.x += v0.x; a0.y += v0.y; a0.z += v0.z; a0.w += v0.w;
      a1.x += v1.x; a1.y += v1.y; a1.z += v1.z; a1.w += v1.w;
    }
    Ysh[ns + 0][i] = a0.x; Ysh[ns + 1][i] = a0.y;
    Ysh[ns + 2][i] = a0.z; Ysh[ns + 3][i] = a0.w;
    Ysh[ns + 4][i] = a1.x; Ysh[ns + 5][i] = a1.y;
    Ysh[ns + 6][i] = a1.z; Ysh[ns + 7][i] = a1.w;
    if (t < 64) {
      float ls = 0.f;
      for (int ks = 0; ks < KS; ++ks)
        ls += Lpart[(size_t)(ks * B_SZ + b) * N_TOK + n0 + t];
      lsh[t] = ls;
    }
  }
  __syncthreads();

  // gate stage 2 (folds 0.8): gsh = 0.8*sigmoid(cg2 @ hl + cg2_b)
  if (t < C_DIM) {
    float z = cg2_b[t];
#pragma unroll
    for (int j = 0; j < BOT; ++j) z += cg2_w[t * BOT + j] * hl[j];
    gsh[t] = 0.8f / (1.f + __expf(-z));
  }
  __syncthreads();

  // phase 2: out = x + gsh*(W_w @ y)/l ; c-range per wave (W reads scalar)
  const int n = t & 63, cg = t >> 6;
  float y[I_DIM];
#pragma unroll
  for (int i = 0; i < I_DIM; ++i) y[i] = Ysh[n][i];
  const float inv = 1.0f / lsh[n];
  const float* xb = x + ((size_t)b * C_DIM + cg * 16) * N_TOK + n0 + n;
  float* ob = out + ((size_t)b * C_DIM + cg * 16) * N_TOK + n0 + n;
#pragma unroll
  for (int c16 = 0; c16 < 16; ++c16) {
    const int c = cg * 16 + c16;
    float sacc = 0.f;
#pragma unroll
    for (int i = 0; i < I_DIM; ++i) sacc += W_w[c * I_DIM + i] * y[i];
    ob[(size_t)c16 * N_TOK] = xb[(size_t)c16 * N_TOK] + gsh[c] * inv * sacc;
  }
}

extern "C" void kernel_launch(void* const* d_in, const int* in_sizes, int n_in,
                              void* d_out, int out_size, void* d_ws, size_t ws_size,
                              hipStream_t stream) {
  const float* x = (const float*)d_in[0];
  const float* g_w = (const float*)d_in[1];
  const float* theta_w = (const float*)d_in[2];
  const float* phi_w = (const float*)d_in[3];
  const float* W_w = (const float*)d_in[4];
  const float* cg1_w = (const float*)d_in[5];
  const float* cg1_b = (const float*)d_in[6];
  const float* cg2_w = (const float*)d_in[7];
  const float* cg2_b = (const float*)d_in[8];
  float* out = (float*)d_out;

  char* w = (char*)d_ws;
  const size_t bfsz = (size_t)B_SZ * N_TOK * I_DIM * sizeof(unsigned short);
  unsigned short* Qb = (unsigned short*)(w);
  unsigned short* Kb = (unsigned short*)(w + bfsz);
  unsigned short* VT = (unsigned short*)(w + 2 * bfsz);
  float* pooled = (float*)(w + 3 * bfsz);
  char* w2 = w + 3 * bfsz + 1024;

  int KS = 16;
  {
    const size_t per = (size_t)B_SZ * N_TOK * sizeof(float) * (I_DIM + 1);
    while (KS > 1 && (3 * bfsz + 1024 + (size_t)KS * per) > ws_size) KS >>= 1;
  }
  float* Lpart = (float*)w2;
  float* Ypart = (float*)(w2 + (size_t)KS * B_SZ * N_TOK * sizeof(float));
  int tps = N_TILES / KS;

  proj_pool_kernel<<<dim3(992), 256, 0, stream>>>(x, g_w, theta_w, phi_w, Qb,
                                                  Kb, VT, pooled);
  attn_kernel<<<dim3(72, KS, B_SZ), 256, 0, stream>>>(Qb, Kb, VT, Ypart, Lpart, tps);
  epilogue_kernel<<<dim3(N_TOK / 64, B_SZ), 256, 0, stream>>>(
      x, W_w, pooled, cg1_w, cg1_b, cg2_w, cg2_b, Ypart, Lpart, out, KS);
}

// Round 5
// 176.311 us; speedup vs baseline: 1.2418x; 1.2418x over previous
//
#include <hip/hip_runtime.h>

#define N_TOK 9216
#define C_DIM 64
#define I_DIM 32
#define BOT 16
#define B_SZ 2
#define N_TILES 144  // N_TOK / 64

typedef short bf16x8 __attribute__((ext_vector_type(8)));
typedef float f32x4 __attribute__((ext_vector_type(4)));
typedef float f32x16 __attribute__((ext_vector_type(16)));

// pack two f32 -> two bf16 (truncation) in one v_perm_b32
__device__ __forceinline__ unsigned packbf(float a, float b) {
  return __builtin_amdgcn_perm(__float_as_uint(b), __float_as_uint(a), 0x07060302u);
}
__device__ __forceinline__ unsigned short bftrunc(float f) {
  return (unsigned short)(__float_as_uint(f) >> 16);
}

// ---------------- fused projections (MFMA 16x16x32) + pooling ----------------
__global__ __launch_bounds__(256) void proj_pool_kernel(
    const float* __restrict__ x, const float* __restrict__ g_w,
    const float* __restrict__ theta_w, const float* __restrict__ phi_w,
    unsigned short* __restrict__ Q, unsigned short* __restrict__ K,
    unsigned short* __restrict__ VT, float* __restrict__ pooled) {
  if (blockIdx.x >= 864) {  // ---- pooling path ----
    int bc = blockIdx.x - 864;  // b*64 + c
    const float* p = x + (size_t)bc * N_TOK;
    float s = 0.f;
    for (int t = threadIdx.x; t < N_TOK; t += 256) s += p[t];
#pragma unroll
    for (int off = 32; off >= 1; off >>= 1) s += __shfl_down(s, off, 64);
    __shared__ float red[4];
    int wid = threadIdx.x >> 6, lane = threadIdx.x & 63;
    if (lane == 0) red[wid] = s;
    __syncthreads();
    if (threadIdx.x == 0)
      pooled[bc] = (red[0] + red[1] + red[2] + red[3]) * (1.0f / N_TOK);
    return;
  }
  const int lane = threadIdx.x & 63;
  const int m = lane & 15, quad = lane >> 4;
  int task = blockIdx.x * 4 + (threadIdx.x >> 6);  // 0..3455
  int mat = task / 1152;
  int r0 = task % 1152;
  int b = r0 / 576;
  int n0 = (r0 % 576) * 16;
  const float* wsrc = (mat == 0) ? theta_w : ((mat == 1) ? phi_w : g_w);
  const float scale = (mat == 0) ? 0.96179669439f : 1.0f;  // log2(e)/1.5

  bf16x8 afr[2][2];  // [itile][cstep] of W
#pragma unroll
  for (int it = 0; it < 2; ++it)
#pragma unroll
    for (int cs = 0; cs < 2; ++cs) {
      const float* wp = wsrc + (it * 16 + m) * C_DIM + cs * 32 + quad * 8;
      union { unsigned u[4]; bf16x8 v; } t;
#pragma unroll
      for (int j = 0; j < 4; ++j)
        t.u[j] = packbf(wp[2 * j] * scale, wp[2 * j + 1] * scale);
      afr[it][cs] = t.v;
    }

  const float* xb = x + (size_t)b * C_DIM * N_TOK + n0 + m;
  bf16x8 bfr[2];
#pragma unroll
  for (int cs = 0; cs < 2; ++cs) {
    union { unsigned u[4]; bf16x8 v; } t;
#pragma unroll
    for (int j = 0; j < 4; ++j) {
      float v0 = xb[(size_t)(cs * 32 + quad * 8 + 2 * j) * N_TOK];
      float v1 = xb[(size_t)(cs * 32 + quad * 8 + 2 * j + 1) * N_TOK];
      t.u[j] = packbf(v0, v1);
    }
    bfr[cs] = t.v;
  }

  f32x4 acc[2] = {{0.f, 0.f, 0.f, 0.f}, {0.f, 0.f, 0.f, 0.f}};
#pragma unroll
  for (int cs = 0; cs < 2; ++cs)
#pragma unroll
    for (int it = 0; it < 2; ++it)
      acc[it] = __builtin_amdgcn_mfma_f32_16x16x32_bf16(afr[it][cs], bfr[cs],
                                                        acc[it], 0, 0, 0);
  // C layout: col(n)=lane&15, row(i)=quad*4+r
  if (mat < 2) {
    unsigned short* dst =
        ((mat == 0) ? Q : K) + ((size_t)b * N_TOK + n0 + m) * I_DIM;
#pragma unroll
    for (int it = 0; it < 2; ++it) {
      unsigned u0 = packbf(acc[it][0], acc[it][1]);
      unsigned u1 = packbf(acc[it][2], acc[it][3]);
      *(uint2*)(dst + it * 16 + quad * 4) = make_uint2(u0, u1);
    }
  } else {
#pragma unroll
    for (int it = 0; it < 2; ++it)
#pragma unroll
      for (int r = 0; r < 4; ++r)
        VT[((size_t)b * I_DIM + it * 16 + quad * 4 + r) * N_TOK + n0 + m] =
            bftrunc(acc[it][r]);
  }
}

// ---- per-32kv-tile work: P=exp2(S^T), transpose via permlane32_swap, Y+=P@V ----
__device__ __forceinline__ void tilework(const f32x16 s, const bf16x8 bvA,
                                         const bf16x8 bvB, f32x16& accy,
                                         float& lsum) {
  float e[16];
#pragma unroll
  for (int r = 0; r < 16; ++r) e[r] = __builtin_amdgcn_exp2f(s[r]);
  float l0 = 0.f, l1 = 0.f, l2 = 0.f, l3 = 0.f;
#pragma unroll
  for (int r = 0; r < 4; ++r) {
    l0 += e[r]; l1 += e[4 + r]; l2 += e[8 + r]; l3 += e[12 + r];
  }
  lsum += (l0 + l1) + (l2 + l3);
  unsigned pk[8];
#pragma unroll
  for (int i = 0; i < 8; ++i) pk[i] = packbf(e[2 * i], e[2 * i + 1]);
  // C-regs (h=lane>>5): pk[0..1]=kv{0..3}+4h, pk[2..3]=kv{8..11}+4h,
  //                     pk[4..5]=kv{16..19}+4h, pk[6..7]=kv{24..27}+4h.
  // permlane32_swap: a' = [a.lo|b.lo], b' = [a.hi|b.hi] -> exact A-fragments.
  asm("v_permlane32_swap_b32 %0, %1" : "+v"(pk[0]), "+v"(pk[2]));
  asm("v_permlane32_swap_b32 %0, %1" : "+v"(pk[1]), "+v"(pk[3]));
  asm("v_permlane32_swap_b32 %0, %1" : "+v"(pk[4]), "+v"(pk[6]));
  asm("v_permlane32_swap_b32 %0, %1" : "+v"(pk[5]), "+v"(pk[7]));
  union { unsigned u[4]; bf16x8 v; } A0, A1;
  A0.u[0] = pk[0]; A0.u[1] = pk[1]; A0.u[2] = pk[2]; A0.u[3] = pk[3];
  A1.u[0] = pk[4]; A1.u[1] = pk[5]; A1.u[2] = pk[6]; A1.u[3] = pk[7];
  accy = __builtin_amdgcn_mfma_f32_32x32x16_bf16(A0.v, bvA, accy, 0, 0, 0);
  accy = __builtin_amdgcn_mfma_f32_32x32x16_bf16(A1.v, bvB, accy, 0, 0, 0);
}

// ---- one 64-kv K-tile: prefetch next K/V into n*, compute from c* ----
__device__ __forceinline__ void attn_step(const bf16x8 bq0, const bf16x8 bq1,
                                          bf16x8 cak[4], bf16x8 cbv[4],
                                          bf16x8 nak[4], bf16x8 nbv[4],
                                          const unsigned short*& kp,
                                          const unsigned short*& vp,
                                          f32x16& accy, float& lsum) {
  const f32x16 zz = {};
  kp += 64 * I_DIM;
  vp += 64;
  nak[0] = *(const bf16x8*)(kp);
  nak[1] = *(const bf16x8*)(kp + 16);
  nak[2] = *(const bf16x8*)(kp + 32 * I_DIM);
  nak[3] = *(const bf16x8*)(kp + 32 * I_DIM + 16);
  nbv[0] = *(const bf16x8*)(vp);
  nbv[1] = *(const bf16x8*)(vp + 16);
  nbv[2] = *(const bf16x8*)(vp + 32);
  nbv[3] = *(const bf16x8*)(vp + 48);

  f32x16 s0 = __builtin_amdgcn_mfma_f32_32x32x16_bf16(cak[0], bq0, zz, 0, 0, 0);
  s0 = __builtin_amdgcn_mfma_f32_32x32x16_bf16(cak[1], bq1, s0, 0, 0, 0);
  f32x16 s1 = __builtin_amdgcn_mfma_f32_32x32x16_bf16(cak[2], bq0, zz, 0, 0, 0);
  s1 = __builtin_amdgcn_mfma_f32_32x32x16_bf16(cak[3], bq1, s1, 0, 0, 0);

  tilework(s0, cbv[0], cbv[1], accy, lsum);
  tilework(s1, cbv[2], cbv[3], accy, lsum);
}

// ---------------- flash attention, S^T form, register-only transpose ----------------
// S^T = K@Q^T via 32x32x16 (D: col q=lane&31, row kv=(reg&3)+8*(reg>>2)+4*(lane>>5)).
// No LDS; K/V double-buffered in registers (prefetch may over-read by one tile,
// which stays inside the workspace). Ypart: [KS][B][N q][32 i].
__global__ __launch_bounds__(256, 4) void attn_kernel(
    const unsigned short* __restrict__ Q, const unsigned short* __restrict__ Kg,
    const unsigned short* __restrict__ VT, float* __restrict__ Ypart,
    float* __restrict__ Lpart, int tps) {
  const int lane = threadIdx.x & 63;
  const int l32 = lane & 31, h = lane >> 5;
  const int qw = blockIdx.x * 4 + (threadIdx.x >> 6);
  const int ks = blockIdx.y, b = blockIdx.z;
  const int q0 = qw * 32;
  const unsigned short* Qb = Q + (size_t)b * N_TOK * I_DIM;
  const unsigned short* Kb = Kg + (size_t)b * N_TOK * I_DIM;
  const unsigned short* Vb = VT + (size_t)b * I_DIM * N_TOK;

  // Q as B-operand: B[k=c][n=q], lane holds q=l32, c=8h+j
  bf16x8 bq0 = *(const bf16x8*)(Qb + (size_t)(q0 + l32) * I_DIM + h * 8);
  bf16x8 bq1 = *(const bf16x8*)(Qb + (size_t)(q0 + l32) * I_DIM + 16 + h * 8);

  f32x16 accy = {};
  float lsum = 0.f;

  const int kt0 = ks * tps;
  const unsigned short* kp = Kb + ((size_t)kt0 * 64 + l32) * I_DIM + h * 8;
  const unsigned short* vp = Vb + (size_t)l32 * N_TOK + kt0 * 64 + h * 8;

  bf16x8 ak[4], bv[4], nak[4], nbv[4];
  ak[0] = *(const bf16x8*)(kp);
  ak[1] = *(const bf16x8*)(kp + 16);
  ak[2] = *(const bf16x8*)(kp + 32 * I_DIM);
  ak[3] = *(const bf16x8*)(kp + 32 * I_DIM + 16);
  bv[0] = *(const bf16x8*)(vp);
  bv[1] = *(const bf16x8*)(vp + 16);
  bv[2] = *(const bf16x8*)(vp + 32);
  bv[3] = *(const bf16x8*)(vp + 48);

  const int half = tps >> 1;  // tps is even for KS in {1,2,4,8}
  for (int it = 0; it < half; ++it) {
    attn_step(bq0, bq1, ak, bv, nak, nbv, kp, vp, accy, lsum);
    attn_step(bq0, bq1, nak, nbv, ak, bv, kp, vp, accy, lsum);
  }

  lsum += __shfl_xor(lsum, 32, 64);

  // accy: D[q][i], col i = l32, row q = (reg&3)+8*(reg>>2)+4h.
  const size_t base = (size_t)(ks * B_SZ + b) * N_TOK + q0;
#pragma unroll
  for (int R = 0; R < 4; ++R)
#pragma unroll
    for (int r = 0; r < 4; ++r)
      Ypart[(base + r + 8 * R + 4 * h) * I_DIM + l32] = accy[4 * R + r];
  if (h == 0) Lpart[base + l32] = lsum;
}

// ---------------- epilogue: gate + reduce partials + GEMV + residual ----------------
__global__ __launch_bounds__(256) void epilogue_kernel(
    const float* __restrict__ x, const float* __restrict__ W_w,
    const float* __restrict__ pooled, const float* __restrict__ cg1_w,
    const float* __restrict__ cg1_b, const float* __restrict__ cg2_w,
    const float* __restrict__ cg2_b, const float* __restrict__ Ypart,
    const float* __restrict__ Lpart, float* __restrict__ out, int KS) {
  __shared__ float Ysh[64][33];
  __shared__ float lsh[64];
  __shared__ float gsh[64];
  __shared__ float hl[BOT];
  const int t = threadIdx.x;
  const int b = blockIdx.y;
  const int n0 = blockIdx.x * 64;

  // gate stage 1: hl = relu(cg1 @ pooled + cg1_b)
  if (t < BOT) {
    float a = cg1_b[t];
#pragma unroll
    for (int c = 0; c < C_DIM; ++c)
      a += cg1_w[t * C_DIM + c] * pooled[b * C_DIM + c];
    hl[t] = a > 0.f ? a : 0.f;
  }

  {  // phase 1: reduce Ypart ([KS][B][N][32]) over KS into Ysh[n][i]
    int nl = t >> 2, i0 = (t & 3) * 8;
    float4 s0 = make_float4(0.f, 0.f, 0.f, 0.f), s1 = s0;
    for (int ks = 0; ks < KS; ++ks) {
      const float* yp =
          Ypart + ((size_t)(ks * B_SZ + b) * N_TOK + n0 + nl) * I_DIM + i0;
      float4 v0 = *(const float4*)(yp);
      float4 v1 = *(const float4*)(yp + 4);
      s0.x += v0.x; s0.y += v0.y; s0.z += v0.z; s0.w += v0.w;
      s1.x += v1.x; s1.y += v1.y; s1.z += v1.z; s1.w += v1.w;
    }
    Ysh[nl][i0 + 0] = s0.x; Ysh[nl][i0 + 1] = s0.y;
    Ysh[nl][i0 + 2] = s0.z; Ysh[nl][i0 + 3] = s0.w;
    Ysh[nl][i0 + 4] = s1.x; Ysh[nl][i0 + 5] = s1.y;
    Ysh[nl][i0 + 6] = s1.z; Ysh[nl][i0 + 7] = s1.w;
    if (t < 64) {
      float ls = 0.f;
      for (int ks = 0; ks < KS; ++ks)
        ls += Lpart[(size_t)(ks * B_SZ + b) * N_TOK + n0 + t];
      lsh[t] = ls;
    }
  }
  __syncthreads();

  // gate stage 2 (folds 0.8): gsh = 0.8*sigmoid(cg2 @ hl + cg2_b)
  if (t < C_DIM) {
    float z = cg2_b[t];
#pragma unroll
    for (int j = 0; j < BOT; ++j) z += cg2_w[t * BOT + j] * hl[j];
    gsh[t] = 0.8f / (1.f + __expf(-z));
  }
  __syncthreads();

  // phase 2: out = x + gsh*(W_w @ y)/l ; c-range per wave (W reads scalar)
  const int n = t & 63, cg = t >> 6;
  float y[I_DIM];
#pragma unroll
  for (int i = 0; i < I_DIM; ++i) y[i] = Ysh[n][i];
  const float inv = 1.0f / lsh[n];
  const float* xb = x + ((size_t)b * C_DIM + cg * 16) * N_TOK + n0 + n;
  float* ob = out + ((size_t)b * C_DIM + cg * 16) * N_TOK + n0 + n;
#pragma unroll
  for (int c16 = 0; c16 < 16; ++c16) {
    const int c = cg * 16 + c16;
    float sacc = 0.f;
#pragma unroll
    for (int i = 0; i < I_DIM; ++i) sacc += W_w[c * I_DIM + i] * y[i];
    ob[(size_t)c16 * N_TOK] = xb[(size_t)c16 * N_TOK] + gsh[c] * inv * sacc;
  }
}

extern "C" void kernel_launch(void* const* d_in, const int* in_sizes, int n_in,
                              void* d_out, int out_size, void* d_ws, size_t ws_size,
                              hipStream_t stream) {
  const float* x = (const float*)d_in[0];
  const float* g_w = (const float*)d_in[1];
  const float* theta_w = (const float*)d_in[2];
  const float* phi_w = (const float*)d_in[3];
  const float* W_w = (const float*)d_in[4];
  const float* cg1_w = (const float*)d_in[5];
  const float* cg1_b = (const float*)d_in[6];
  const float* cg2_w = (const float*)d_in[7];
  const float* cg2_b = (const float*)d_in[8];
  float* out = (float*)d_out;

  char* w = (char*)d_ws;
  const size_t bfsz = (size_t)B_SZ * N_TOK * I_DIM * sizeof(unsigned short);
  unsigned short* Qb = (unsigned short*)(w);
  unsigned short* Kb = (unsigned short*)(w + bfsz);
  unsigned short* VT = (unsigned short*)(w + 2 * bfsz);
  float* pooled = (float*)(w + 3 * bfsz);
  char* w2 = w + 3 * bfsz + 4096;  // slack: attn prefetch may over-read one tile

  int KS = 8;
  {
    const size_t per = (size_t)B_SZ * N_TOK * sizeof(float) * (I_DIM + 1);
    while (KS > 1 && (3 * bfsz + 4096 + (size_t)KS * per) > ws_size) KS >>= 1;
  }
  float* Lpart = (float*)w2;
  float* Ypart = (float*)(w2 + (size_t)KS * B_SZ * N_TOK * sizeof(float));
  int tps = N_TILES / KS;

  proj_pool_kernel<<<dim3(992), 256, 0, stream>>>(x, g_w, theta_w, phi_w, Qb,
                                                  Kb, VT, pooled);
  attn_kernel<<<dim3(72, KS, B_SZ), 256, 0, stream>>>(Qb, Kb, VT, Ypart, Lpart, tps);
  epilogue_kernel<<<dim3(N_TOK / 64, B_SZ), 256, 0, stream>>>(
      x, W_w, pooled, cg1_w, cg1_b, cg2_w, cg2_b, Ypart, Lpart, out, KS);
}

// Round 6
// 175.427 us; speedup vs baseline: 1.2481x; 1.0050x over previous
//
#include <hip/hip_runtime.h>

#define N_TOK 9216
#define C_DIM 64
#define I_DIM 32
#define BOT 16
#define B_SZ 2
#define N_TILES 144  // N_TOK / 64

typedef short bf16x8 __attribute__((ext_vector_type(8)));
typedef float f32x4 __attribute__((ext_vector_type(4)));
typedef float f32x16 __attribute__((ext_vector_type(16)));

// pack two f32 -> two bf16 (truncation) in one v_perm_b32
__device__ __forceinline__ unsigned packbf(float a, float b) {
  return __builtin_amdgcn_perm(__float_as_uint(b), __float_as_uint(a), 0x07060302u);
}
__device__ __forceinline__ unsigned short bftrunc(float f) {
  return (unsigned short)(__float_as_uint(f) >> 16);
}
__device__ __forceinline__ float bflo(unsigned u) {
  return __uint_as_float(u << 16);
}
__device__ __forceinline__ float bfhi(unsigned u) {
  return __uint_as_float(u & 0xffff0000u);
}

// ---------------- fused projections (MFMA 16x16x32) + pooling ----------------
__global__ __launch_bounds__(256) void proj_pool_kernel(
    const float* __restrict__ x, const float* __restrict__ g_w,
    const float* __restrict__ theta_w, const float* __restrict__ phi_w,
    unsigned short* __restrict__ Q, unsigned short* __restrict__ K,
    unsigned short* __restrict__ VT, float* __restrict__ pooled) {
  if (blockIdx.x >= 864) {  // ---- pooling path ----
    int bc = blockIdx.x - 864;  // b*64 + c
    const float* p = x + (size_t)bc * N_TOK;
    float s = 0.f;
    for (int t = threadIdx.x; t < N_TOK; t += 256) s += p[t];
#pragma unroll
    for (int off = 32; off >= 1; off >>= 1) s += __shfl_down(s, off, 64);
    __shared__ float red[4];
    int wid = threadIdx.x >> 6, lane = threadIdx.x & 63;
    if (lane == 0) red[wid] = s;
    __syncthreads();
    if (threadIdx.x == 0)
      pooled[bc] = (red[0] + red[1] + red[2] + red[3]) * (1.0f / N_TOK);
    return;
  }
  const int lane = threadIdx.x & 63;
  const int m = lane & 15, quad = lane >> 4;
  int task = blockIdx.x * 4 + (threadIdx.x >> 6);  // 0..3455
  int mat = task / 1152;
  int r0 = task % 1152;
  int b = r0 / 576;
  int n0 = (r0 % 576) * 16;
  const float* wsrc = (mat == 0) ? theta_w : ((mat == 1) ? phi_w : g_w);
  const float scale = (mat == 0) ? 0.96179669439f : 1.0f;  // log2(e)/1.5

  bf16x8 afr[2][2];  // [itile][cstep] of W
#pragma unroll
  for (int it = 0; it < 2; ++it)
#pragma unroll
    for (int cs = 0; cs < 2; ++cs) {
      const float* wp = wsrc + (it * 16 + m) * C_DIM + cs * 32 + quad * 8;
      union { unsigned u[4]; bf16x8 v; } t;
#pragma unroll
      for (int j = 0; j < 4; ++j)
        t.u[j] = packbf(wp[2 * j] * scale, wp[2 * j + 1] * scale);
      afr[it][cs] = t.v;
    }

  const float* xb = x + (size_t)b * C_DIM * N_TOK + n0 + m;
  bf16x8 bfr[2];
#pragma unroll
  for (int cs = 0; cs < 2; ++cs) {
    union { unsigned u[4]; bf16x8 v; } t;
#pragma unroll
    for (int j = 0; j < 4; ++j) {
      float v0 = xb[(size_t)(cs * 32 + quad * 8 + 2 * j) * N_TOK];
      float v1 = xb[(size_t)(cs * 32 + quad * 8 + 2 * j + 1) * N_TOK];
      t.u[j] = packbf(v0, v1);
    }
    bfr[cs] = t.v;
  }

  f32x4 acc[2] = {{0.f, 0.f, 0.f, 0.f}, {0.f, 0.f, 0.f, 0.f}};
#pragma unroll
  for (int cs = 0; cs < 2; ++cs)
#pragma unroll
    for (int it = 0; it < 2; ++it)
      acc[it] = __builtin_amdgcn_mfma_f32_16x16x32_bf16(afr[it][cs], bfr[cs],
                                                        acc[it], 0, 0, 0);
  // C layout: col(n)=lane&15, row(i)=quad*4+r
  if (mat < 2) {
    unsigned short* dst =
        ((mat == 0) ? Q : K) + ((size_t)b * N_TOK + n0 + m) * I_DIM;
#pragma unroll
    for (int it = 0; it < 2; ++it) {
      unsigned u0 = packbf(acc[it][0], acc[it][1]);
      unsigned u1 = packbf(acc[it][2], acc[it][3]);
      *(uint2*)(dst + it * 16 + quad * 4) = make_uint2(u0, u1);
    }
  } else {
#pragma unroll
    for (int it = 0; it < 2; ++it)
#pragma unroll
      for (int r = 0; r < 4; ++r)
        VT[((size_t)b * I_DIM + it * 16 + quad * 4 + r) * N_TOK + n0 + m] =
            bftrunc(acc[it][r]);
  }
}

// ---- per-32kv-tile work: P=exp2(S^T), transpose via permlane32_swap, Y+=P@V ----
__device__ __forceinline__ void tilework(const f32x16 s, const bf16x8 bvA,
                                         const bf16x8 bvB, f32x16& accy,
                                         float& lsum) {
  float e[16];
#pragma unroll
  for (int r = 0; r < 16; ++r) e[r] = __builtin_amdgcn_exp2f(s[r]);
  float l0 = 0.f, l1 = 0.f, l2 = 0.f, l3 = 0.f;
#pragma unroll
  for (int r = 0; r < 4; ++r) {
    l0 += e[r]; l1 += e[4 + r]; l2 += e[8 + r]; l3 += e[12 + r];
  }
  lsum += (l0 + l1) + (l2 + l3);
  unsigned pk[8];
#pragma unroll
  for (int i = 0; i < 8; ++i) pk[i] = packbf(e[2 * i], e[2 * i + 1]);
  // C-regs (h=lane>>5): pk[0..1]=kv{0..3}+4h, pk[2..3]=kv{8..11}+4h,
  //                     pk[4..5]=kv{16..19}+4h, pk[6..7]=kv{24..27}+4h.
  // permlane32_swap: a' = [a.lo|b.lo], b' = [a.hi|b.hi] -> exact A-fragments.
  asm("v_permlane32_swap_b32 %0, %1" : "+v"(pk[0]), "+v"(pk[2]));
  asm("v_permlane32_swap_b32 %0, %1" : "+v"(pk[1]), "+v"(pk[3]));
  asm("v_permlane32_swap_b32 %0, %1" : "+v"(pk[4]), "+v"(pk[6]));
  asm("v_permlane32_swap_b32 %0, %1" : "+v"(pk[5]), "+v"(pk[7]));
  union { unsigned u[4]; bf16x8 v; } A0, A1;
  A0.u[0] = pk[0]; A0.u[1] = pk[1]; A0.u[2] = pk[2]; A0.u[3] = pk[3];
  A1.u[0] = pk[4]; A1.u[1] = pk[5]; A1.u[2] = pk[6]; A1.u[3] = pk[7];
  accy = __builtin_amdgcn_mfma_f32_32x32x16_bf16(A0.v, bvA, accy, 0, 0, 0);
  accy = __builtin_amdgcn_mfma_f32_32x32x16_bf16(A1.v, bvB, accy, 0, 0, 0);
}

__device__ __forceinline__ void loadK(bf16x8 a[4], const unsigned short* kp) {
  a[0] = *(const bf16x8*)(kp);
  a[1] = *(const bf16x8*)(kp + 16);
  a[2] = *(const bf16x8*)(kp + 32 * I_DIM);
  a[3] = *(const bf16x8*)(kp + 32 * I_DIM + 16);
}

// ---------------- flash attention, S^T form, register-only transpose ----------------
// S^T = K@Q^T via 32x32x16 (D: col q=lane&31, row kv=(reg&3)+8*(reg>>2)+4*(lane>>5)).
// K register double-buffered (prefetch may over-read one tile: stays inside ws).
// V loaded early each iteration, consumed late (latency hidden by S+exp chain).
// Ypart: [KS][B][N q][32 i] bf16. Lpart: [KS][B][N] f32.
__global__ __launch_bounds__(256, 4) void attn_kernel(
    const unsigned short* __restrict__ Q, const unsigned short* __restrict__ Kg,
    const unsigned short* __restrict__ VT, unsigned short* __restrict__ Ypart,
    float* __restrict__ Lpart, int tps) {
  const int lane = threadIdx.x & 63;
  const int l32 = lane & 31, h = lane >> 5;
  const int qw = blockIdx.x * 4 + (threadIdx.x >> 6);
  const int ks = blockIdx.y, b = blockIdx.z;
  const int q0 = qw * 32;
  const unsigned short* Qb = Q + (size_t)b * N_TOK * I_DIM;
  const unsigned short* Kb = Kg + (size_t)b * N_TOK * I_DIM;
  const unsigned short* Vb = VT + (size_t)b * I_DIM * N_TOK;

  // Q as B-operand: B[k=c][n=q], lane holds q=l32, c=8h+j
  bf16x8 bq0 = *(const bf16x8*)(Qb + (size_t)(q0 + l32) * I_DIM + h * 8);
  bf16x8 bq1 = *(const bf16x8*)(Qb + (size_t)(q0 + l32) * I_DIM + 16 + h * 8);

  f32x16 accy = {};
  float lsum = 0.f;

  const int kt0 = ks * tps;
  const unsigned short* kp = Kb + ((size_t)kt0 * 64 + l32) * I_DIM + h * 8;
  const unsigned short* vp0 = Vb + (size_t)l32 * N_TOK + kt0 * 64 + h * 8;

  const f32x16 zz = {};
  bf16x8 ak[4];
  loadK(ak, kp);
  for (int kt = 0; kt < tps; ++kt) {
    kp += 64 * I_DIM;
    bf16x8 nak[4];
    loadK(nak, kp);  // prefetch next K tile (over-reads once at the end; unused)
    const unsigned short* vp = vp0 + kt * 64;
    bf16x8 bv0 = *(const bf16x8*)(vp);
    bf16x8 bv1 = *(const bf16x8*)(vp + 16);
    bf16x8 bv2 = *(const bf16x8*)(vp + 32);
    bf16x8 bv3 = *(const bf16x8*)(vp + 48);

    f32x16 s0 = __builtin_amdgcn_mfma_f32_32x32x16_bf16(ak[0], bq0, zz, 0, 0, 0);
    s0 = __builtin_amdgcn_mfma_f32_32x32x16_bf16(ak[1], bq1, s0, 0, 0, 0);
    f32x16 s1 = __builtin_amdgcn_mfma_f32_32x32x16_bf16(ak[2], bq0, zz, 0, 0, 0);
    s1 = __builtin_amdgcn_mfma_f32_32x32x16_bf16(ak[3], bq1, s1, 0, 0, 0);

    tilework(s0, bv0, bv1, accy, lsum);
    tilework(s1, bv2, bv3, accy, lsum);

    ak[0] = nak[0]; ak[1] = nak[1]; ak[2] = nak[2]; ak[3] = nak[3];
  }

  lsum += __shfl_xor(lsum, 32, 64);

  // accy: D[q][i], col i = l32, row q = (reg&3)+8*(reg>>2)+4h.
  const size_t base = (size_t)(ks * B_SZ + b) * N_TOK + q0;
#pragma unroll
  for (int R = 0; R < 4; ++R)
#pragma unroll
    for (int r = 0; r < 4; ++r)
      Ypart[(base + r + 8 * R + 4 * h) * I_DIM + l32] = bftrunc(accy[4 * R + r]);
  if (h == 0) Lpart[base + l32] = lsum;
}

// ---------------- epilogue: gate + reduce partials + GEMV + residual ----------------
__global__ __launch_bounds__(256) void epilogue_kernel(
    const float* __restrict__ x, const float* __restrict__ W_w,
    const float* __restrict__ pooled, const float* __restrict__ cg1_w,
    const float* __restrict__ cg1_b, const float* __restrict__ cg2_w,
    const float* __restrict__ cg2_b, const unsigned short* __restrict__ Ypart,
    const float* __restrict__ Lpart, float* __restrict__ out, int KS) {
  __shared__ float Ysh[64][33];
  __shared__ float lsh[64];
  __shared__ float gsh[64];
  __shared__ float hl[BOT];
  const int t = threadIdx.x;
  const int b = blockIdx.y;
  const int n0 = blockIdx.x * 64;

  // gate stage 1: hl = relu(cg1 @ pooled + cg1_b)
  if (t < BOT) {
    float a = cg1_b[t];
#pragma unroll
    for (int c = 0; c < C_DIM; ++c)
      a += cg1_w[t * C_DIM + c] * pooled[b * C_DIM + c];
    hl[t] = a > 0.f ? a : 0.f;
  }

  {  // phase 1: reduce Ypart ([KS][B][N][32] bf16) over KS into Ysh[n][i]
    int nl = t >> 2, i0 = (t & 3) * 8;
    float s[8];
#pragma unroll
    for (int k = 0; k < 8; ++k) s[k] = 0.f;
    for (int ks = 0; ks < KS; ++ks) {
      const unsigned short* yp =
          Ypart + ((size_t)(ks * B_SZ + b) * N_TOK + n0 + nl) * I_DIM + i0;
      uint4 v = *(const uint4*)yp;  // 8 bf16
      s[0] += bflo(v.x); s[1] += bfhi(v.x);
      s[2] += bflo(v.y); s[3] += bfhi(v.y);
      s[4] += bflo(v.z); s[5] += bfhi(v.z);
      s[6] += bflo(v.w); s[7] += bfhi(v.w);
    }
#pragma unroll
    for (int k = 0; k < 8; ++k) Ysh[nl][i0 + k] = s[k];
    if (t < 64) {
      float ls = 0.f;
      for (int ks = 0; ks < KS; ++ks)
        ls += Lpart[(size_t)(ks * B_SZ + b) * N_TOK + n0 + t];
      lsh[t] = ls;
    }
  }
  __syncthreads();

  // gate stage 2 (folds 0.8): gsh = 0.8*sigmoid(cg2 @ hl + cg2_b)
  if (t < C_DIM) {
    float z = cg2_b[t];
#pragma unroll
    for (int j = 0; j < BOT; ++j) z += cg2_w[t * BOT + j] * hl[j];
    gsh[t] = 0.8f / (1.f + __expf(-z));
  }
  __syncthreads();

  // phase 2: out = x + gsh*(W_w @ y)/l ; c-range per wave (W reads scalar)
  const int n = t & 63, cg = t >> 6;
  float y[I_DIM];
#pragma unroll
  for (int i = 0; i < I_DIM; ++i) y[i] = Ysh[n][i];
  const float inv = 1.0f / lsh[n];
  const float* xb = x + ((size_t)b * C_DIM + cg * 16) * N_TOK + n0 + n;
  float* ob = out + ((size_t)b * C_DIM + cg * 16) * N_TOK + n0 + n;
#pragma unroll
  for (int c16 = 0; c16 < 16; ++c16) {
    const int c = cg * 16 + c16;
    float sacc = 0.f;
#pragma unroll
    for (int i = 0; i < I_DIM; ++i) sacc += W_w[c * I_DIM + i] * y[i];
    ob[(size_t)c16 * N_TOK] = xb[(size_t)c16 * N_TOK] + gsh[c] * inv * sacc;
  }
}

extern "C" void kernel_launch(void* const* d_in, const int* in_sizes, int n_in,
                              void* d_out, int out_size, void* d_ws, size_t ws_size,
                              hipStream_t stream) {
  const float* x = (const float*)d_in[0];
  const float* g_w = (const float*)d_in[1];
  const float* theta_w = (const float*)d_in[2];
  const float* phi_w = (const float*)d_in[3];
  const float* W_w = (const float*)d_in[4];
  const float* cg1_w = (const float*)d_in[5];
  const float* cg1_b = (const float*)d_in[6];
  const float* cg2_w = (const float*)d_in[7];
  const float* cg2_b = (const float*)d_in[8];
  float* out = (float*)d_out;

  char* w = (char*)d_ws;
  const size_t bfsz = (size_t)B_SZ * N_TOK * I_DIM * sizeof(unsigned short);
  unsigned short* Qb = (unsigned short*)(w);
  unsigned short* Kb = (unsigned short*)(w + bfsz);
  unsigned short* VT = (unsigned short*)(w + 2 * bfsz);
  float* pooled = (float*)(w + 3 * bfsz);
  char* w2 = w + 3 * bfsz + 8192;  // slack: attn K-prefetch may over-read one tile

  int KS = 16;
  {
    // per split: Ypart bf16 (B*N*32*2) + Lpart f32 (B*N*4)
    const size_t per = (size_t)B_SZ * N_TOK * (I_DIM * 2 + 4);
    while (KS > 1 && (3 * bfsz + 8192 + (size_t)KS * per) > ws_size) KS >>= 1;
  }
  float* Lpart = (float*)w2;
  unsigned short* Ypart =
      (unsigned short*)(w2 + (size_t)KS * B_SZ * N_TOK * sizeof(float));
  int tps = N_TILES / KS;

  proj_pool_kernel<<<dim3(992), 256, 0, stream>>>(x, g_w, theta_w, phi_w, Qb,
                                                  Kb, VT, pooled);
  attn_kernel<<<dim3(72, KS, B_SZ), 256, 0, stream>>>(Qb, Kb, VT, Ypart, Lpart, tps);
  epilogue_kernel<<<dim3(N_TOK / 64, B_SZ), 256, 0, stream>>>(
      x, W_w, pooled, cg1_w, cg1_b, cg2_w, cg2_b, Ypart, Lpart, out, KS);
}

// Round 7
// 142.233 us; speedup vs baseline: 1.5394x; 1.2334x over previous
//
#include <hip/hip_runtime.h>

#define N_TOK 9216
#define C_DIM 64
#define I_DIM 32
#define BOT 16
#define B_SZ 2
#define N_TILES 144  // N_TOK / 64

typedef short bf16x8 __attribute__((ext_vector_type(8)));
typedef float f32x4 __attribute__((ext_vector_type(4)));
typedef float f32x16 __attribute__((ext_vector_type(16)));

#define KST 36  // LDS row stride (elements) for K tile rows (64 rows x 32 el)
#define VST 68  // LDS row stride (elements) for V tile rows (32 rows x 64 el)

// pack two f32 -> two bf16 (truncation) in one v_perm_b32
__device__ __forceinline__ unsigned packbf(float a, float b) {
  return __builtin_amdgcn_perm(__float_as_uint(b), __float_as_uint(a), 0x07060302u);
}
__device__ __forceinline__ unsigned short bftrunc(float f) {
  return (unsigned short)(__float_as_uint(f) >> 16);
}
__device__ __forceinline__ float bflo(unsigned u) {
  return __uint_as_float(u << 16);
}
__device__ __forceinline__ float bfhi(unsigned u) {
  return __uint_as_float(u & 0xffff0000u);
}

// ---------------- fused projections (MFMA 16x16x32, 64-token tasks) + pooling ----------------
// tasks 0..863: (mat, b, 64-token tile); mat0=theta (scaled log2e/T), mat1=phi, mat2=g.
// Q/K: [B][N][32] bf16 row-major. VT: [B][32][N] bf16.
__global__ __launch_bounds__(256) void proj_pool_kernel(
    const float* __restrict__ x, const float* __restrict__ g_w,
    const float* __restrict__ theta_w, const float* __restrict__ phi_w,
    unsigned short* __restrict__ Q, unsigned short* __restrict__ K,
    unsigned short* __restrict__ VT, float* __restrict__ pooled) {
  if (blockIdx.x >= 216) {  // ---- pooling path ----
    int bc = blockIdx.x - 216;  // b*64 + c
    const float* p = x + (size_t)bc * N_TOK;
    float s = 0.f;
    for (int t = threadIdx.x; t < N_TOK; t += 256) s += p[t];
#pragma unroll
    for (int off = 32; off >= 1; off >>= 1) s += __shfl_down(s, off, 64);
    __shared__ float red[4];
    int wid = threadIdx.x >> 6, lane = threadIdx.x & 63;
    if (lane == 0) red[wid] = s;
    __syncthreads();
    if (threadIdx.x == 0)
      pooled[bc] = (red[0] + red[1] + red[2] + red[3]) * (1.0f / N_TOK);
    return;
  }
  const int lane = threadIdx.x & 63;
  const int m = lane & 15, quad = lane >> 4;
  int task = blockIdx.x * 4 + (threadIdx.x >> 6);  // 0..863
  int mat = task / 288;
  int r0 = task % 288;
  int b = r0 / 144;
  int n0 = (r0 % 144) * 64;
  const float* wsrc = (mat == 0) ? theta_w : ((mat == 1) ? phi_w : g_w);
  const float scale = (mat == 0) ? 0.96179669439f : 1.0f;  // log2(e)/1.5

  bf16x8 afr[2][2];  // [itile][cstep] of W (held across all 4 sub-tiles)
#pragma unroll
  for (int it = 0; it < 2; ++it)
#pragma unroll
    for (int cs = 0; cs < 2; ++cs) {
      const float* wp = wsrc + (it * 16 + m) * C_DIM + cs * 32 + quad * 8;
      union { unsigned u[4]; bf16x8 v; } t;
#pragma unroll
      for (int j = 0; j < 4; ++j)
        t.u[j] = packbf(wp[2 * j] * scale, wp[2 * j + 1] * scale);
      afr[it][cs] = t.v;
    }

#pragma unroll
  for (int sub = 0; sub < 4; ++sub) {
    const int ns = n0 + sub * 16;
    const float* xb = x + (size_t)b * C_DIM * N_TOK + ns + m;
    bf16x8 bfr[2];
#pragma unroll
    for (int cs = 0; cs < 2; ++cs) {
      union { unsigned u[4]; bf16x8 v; } t;
#pragma unroll
      for (int j = 0; j < 4; ++j) {
        float v0 = xb[(size_t)(cs * 32 + quad * 8 + 2 * j) * N_TOK];
        float v1 = xb[(size_t)(cs * 32 + quad * 8 + 2 * j + 1) * N_TOK];
        t.u[j] = packbf(v0, v1);
      }
      bfr[cs] = t.v;
    }

    f32x4 acc[2] = {{0.f, 0.f, 0.f, 0.f}, {0.f, 0.f, 0.f, 0.f}};
#pragma unroll
    for (int cs = 0; cs < 2; ++cs)
#pragma unroll
      for (int it = 0; it < 2; ++it)
        acc[it] = __builtin_amdgcn_mfma_f32_16x16x32_bf16(afr[it][cs], bfr[cs],
                                                          acc[it], 0, 0, 0);
    // C layout: col(n)=lane&15, row(i)=quad*4+r
    if (mat < 2) {
      unsigned short* dst =
          ((mat == 0) ? Q : K) + ((size_t)b * N_TOK + ns + m) * I_DIM;
#pragma unroll
      for (int it = 0; it < 2; ++it) {
        unsigned u0 = packbf(acc[it][0], acc[it][1]);
        unsigned u1 = packbf(acc[it][2], acc[it][3]);
        *(uint2*)(dst + it * 16 + quad * 4) = make_uint2(u0, u1);
      }
    } else {
#pragma unroll
      for (int it = 0; it < 2; ++it)
#pragma unroll
        for (int r = 0; r < 4; ++r)
          VT[((size_t)b * I_DIM + it * 16 + quad * 4 + r) * N_TOK + ns + m] =
              bftrunc(acc[it][r]);
    }
  }
}

// ---- per-32kv-tile work: P=exp2(S^T), transpose via permlane32_swap, Y+=P@V ----
__device__ __forceinline__ void tilework(const f32x16 s, const bf16x8 bvA,
                                         const bf16x8 bvB, f32x16& accy,
                                         float& lsum) {
  float e[16];
#pragma unroll
  for (int r = 0; r < 16; ++r) e[r] = __builtin_amdgcn_exp2f(s[r]);
  float l0 = 0.f, l1 = 0.f, l2 = 0.f, l3 = 0.f;
#pragma unroll
  for (int r = 0; r < 4; ++r) {
    l0 += e[r]; l1 += e[4 + r]; l2 += e[8 + r]; l3 += e[12 + r];
  }
  lsum += (l0 + l1) + (l2 + l3);
  unsigned pk[8];
#pragma unroll
  for (int i = 0; i < 8; ++i) pk[i] = packbf(e[2 * i], e[2 * i + 1]);
  // C-regs (h=lane>>5): pk[0..1]=kv{0..3}+4h, pk[2..3]=kv{8..11}+4h,
  //                     pk[4..5]=kv{16..19}+4h, pk[6..7]=kv{24..27}+4h.
  // permlane32_swap: a' = [a.lo|b.lo], b' = [a.hi|b.hi] -> exact A-fragments.
  asm("v_permlane32_swap_b32 %0, %1" : "+v"(pk[0]), "+v"(pk[2]));
  asm("v_permlane32_swap_b32 %0, %1" : "+v"(pk[1]), "+v"(pk[3]));
  asm("v_permlane32_swap_b32 %0, %1" : "+v"(pk[4]), "+v"(pk[6]));
  asm("v_permlane32_swap_b32 %0, %1" : "+v"(pk[5]), "+v"(pk[7]));
  union { unsigned u[4]; bf16x8 v; } A0, A1;
  A0.u[0] = pk[0]; A0.u[1] = pk[1]; A0.u[2] = pk[2]; A0.u[3] = pk[3];
  A1.u[0] = pk[4]; A1.u[1] = pk[5]; A1.u[2] = pk[6]; A1.u[3] = pk[7];
  accy = __builtin_amdgcn_mfma_f32_32x32x16_bf16(A0.v, bvA, accy, 0, 0, 0);
  accy = __builtin_amdgcn_mfma_f32_32x32x16_bf16(A1.v, bvB, accy, 0, 0, 0);
}

__device__ __forceinline__ bf16x8 lds_frag(const unsigned short* p) {
  union { uint2 d[2]; bf16x8 v; } t;
  t.d[0] = *(const uint2*)(p);
  t.d[1] = *(const uint2*)(p + 4);
  return t.v;
}

// ---------------- flash attention: block-shared LDS K/V staging ----------------
// Block = 4 waves x 32q = 128 q rows, all sharing each 64-kv tile (4x less L2
// traffic). Staging: load next tile -> regs at loop top (in flight through the
// compute phase; waitcnt lands at the ds_write after the compute), write to LDS
// after the read-barrier. S^T = K@Q^T via 32x32x16; P transposed in-register
// via permlane32_swap. Ypart: [KS][B][N q][32 i] bf16. Lpart: [KS][B][N] f32.
__global__ __launch_bounds__(256, 4) void attn_kernel(
    const unsigned short* __restrict__ Q, const unsigned short* __restrict__ Kg,
    const unsigned short* __restrict__ VT, unsigned short* __restrict__ Ypart,
    float* __restrict__ Lpart, int tps) {
  const int tid = threadIdx.x;
  const int lane = tid & 63;
  const int l32 = lane & 31, h = lane >> 5;
  const int ks = blockIdx.y, b = blockIdx.z;
  const int q0 = blockIdx.x * 128 + (tid >> 6) * 32;
  const unsigned short* Qb = Q + (size_t)b * N_TOK * I_DIM;
  const unsigned short* Kb = Kg + (size_t)b * N_TOK * I_DIM;
  const unsigned short* Vb = VT + (size_t)b * I_DIM * N_TOK;

  __shared__ __align__(16) unsigned short Ks[64 * KST];
  __shared__ __align__(16) unsigned short Vs[32 * VST];

  // Q as B-operand: B[k=c][n=q], lane holds q=l32, c=8h+j
  bf16x8 bq0 = *(const bf16x8*)(Qb + (size_t)(q0 + l32) * I_DIM + h * 8);
  bf16x8 bq1 = *(const bf16x8*)(Qb + (size_t)(q0 + l32) * I_DIM + 16 + h * 8);

  f32x16 accy = {};
  float lsum = 0.f;
  const f32x16 zz = {};

  const int kt0 = ks * tps;
  // staging addresses: thread t stages 16B of K and 16B of V per tile
  const int kr = tid >> 2, kc = (tid & 3) * 8;   // K: 64 rows x 32 el
  const int vr = tid >> 3, vc = (tid & 7) * 8;   // V: 32 rows x 64 el
  const unsigned short* kgp = Kb + ((size_t)kt0 * 64 + kr) * I_DIM + kc;
  const unsigned short* vgp = Vb + (size_t)vr * N_TOK + kt0 * 64 + vc;
  unsigned short* klp = &Ks[kr * KST + kc];
  unsigned short* vlp = &Vs[vr * VST + vc];

  {  // prologue: stage tile 0
    uint4 rk = *(const uint4*)kgp;
    uint4 rv = *(const uint4*)vgp;
    *(uint2*)(klp) = make_uint2(rk.x, rk.y);
    *(uint2*)(klp + 4) = make_uint2(rk.z, rk.w);
    *(uint2*)(vlp) = make_uint2(rv.x, rv.y);
    *(uint2*)(vlp + 4) = make_uint2(rv.z, rv.w);
  }

  for (int kt = 0; kt < tps; ++kt) {
    __syncthreads();  // staged tile kt visible
    const bool pf = (kt + 1 < tps);
    uint4 rk = {0, 0, 0, 0}, rv = {0, 0, 0, 0};
    if (pf) {
      rk = *(const uint4*)(kgp + (size_t)(kt + 1) * 64 * I_DIM);
      rv = *(const uint4*)(vgp + (kt + 1) * 64);
    }
    asm volatile("" ::: "memory");  // pin load issue before the compute phase

    // ---- compute tile kt from LDS ----
    bf16x8 ak00 = lds_frag(&Ks[l32 * KST + 8 * h]);
    bf16x8 ak01 = lds_frag(&Ks[l32 * KST + 16 + 8 * h]);
    bf16x8 ak10 = lds_frag(&Ks[(32 + l32) * KST + 8 * h]);
    bf16x8 ak11 = lds_frag(&Ks[(32 + l32) * KST + 16 + 8 * h]);
    bf16x8 bv0 = lds_frag(&Vs[l32 * VST + 8 * h]);
    bf16x8 bv1 = lds_frag(&Vs[l32 * VST + 16 + 8 * h]);
    bf16x8 bv2 = lds_frag(&Vs[l32 * VST + 32 + 8 * h]);
    bf16x8 bv3 = lds_frag(&Vs[l32 * VST + 48 + 8 * h]);

    f32x16 s0 = __builtin_amdgcn_mfma_f32_32x32x16_bf16(ak00, bq0, zz, 0, 0, 0);
    s0 = __builtin_amdgcn_mfma_f32_32x32x16_bf16(ak01, bq1, s0, 0, 0, 0);
    f32x16 s1 = __builtin_amdgcn_mfma_f32_32x32x16_bf16(ak10, bq0, zz, 0, 0, 0);
    s1 = __builtin_amdgcn_mfma_f32_32x32x16_bf16(ak11, bq1, s1, 0, 0, 0);

    tilework(s0, bv0, bv1, accy, lsum);
    tilework(s1, bv2, bv3, accy, lsum);

    __syncthreads();  // all reads of tile kt complete
    if (pf) {
      *(uint2*)(klp) = make_uint2(rk.x, rk.y);
      *(uint2*)(klp + 4) = make_uint2(rk.z, rk.w);
      *(uint2*)(vlp) = make_uint2(rv.x, rv.y);
      *(uint2*)(vlp + 4) = make_uint2(rv.z, rv.w);
    }
  }

  lsum += __shfl_xor(lsum, 32, 64);

  // accy: D[q][i], col i = l32, row q = (reg&3)+8*(reg>>2)+4h.
  const size_t base = (size_t)(ks * B_SZ + b) * N_TOK + q0;
#pragma unroll
  for (int R = 0; R < 4; ++R)
#pragma unroll
    for (int r = 0; r < 4; ++r)
      Ypart[(base + r + 8 * R + 4 * h) * I_DIM + l32] = bftrunc(accy[4 * R + r]);
  if (h == 0) Lpart[base + l32] = lsum;
}

// ---------------- epilogue: gate + reduce partials + GEMV + residual ----------------
__global__ __launch_bounds__(256) void epilogue_kernel(
    const float* __restrict__ x, const float* __restrict__ W_w,
    const float* __restrict__ pooled, const float* __restrict__ cg1_w,
    const float* __restrict__ cg1_b, const float* __restrict__ cg2_w,
    const float* __restrict__ cg2_b, const unsigned short* __restrict__ Ypart,
    const float* __restrict__ Lpart, float* __restrict__ out, int KS) {
  __shared__ float Ysh[64][33];
  __shared__ float lsh[64];
  __shared__ float gsh[64];
  __shared__ float hl[BOT];
  const int t = threadIdx.x;
  const int b = blockIdx.y;
  const int n0 = blockIdx.x * 64;

  // gate stage 1: hl = relu(cg1 @ pooled + cg1_b)
  if (t < BOT) {
    float a = cg1_b[t];
#pragma unroll
    for (int c = 0; c < C_DIM; ++c)
      a += cg1_w[t * C_DIM + c] * pooled[b * C_DIM + c];
    hl[t] = a > 0.f ? a : 0.f;
  }

  {  // phase 1: reduce Ypart ([KS][B][N][32] bf16) over KS into Ysh[n][i]
    int nl = t >> 2, i0 = (t & 3) * 8;
    float s[8];
#pragma unroll
    for (int k = 0; k < 8; ++k) s[k] = 0.f;
    for (int ks = 0; ks < KS; ++ks) {
      const unsigned short* yp =
          Ypart + ((size_t)(ks * B_SZ + b) * N_TOK + n0 + nl) * I_DIM + i0;
      uint4 v = *(const uint4*)yp;  // 8 bf16
      s[0] += bflo(v.x); s[1] += bfhi(v.x);
      s[2] += bflo(v.y); s[3] += bfhi(v.y);
      s[4] += bflo(v.z); s[5] += bfhi(v.z);
      s[6] += bflo(v.w); s[7] += bfhi(v.w);
    }
#pragma unroll
    for (int k = 0; k < 8; ++k) Ysh[nl][i0 + k] = s[k];
    if (t < 64) {
      float ls = 0.f;
      for (int ks = 0; ks < KS; ++ks)
        ls += Lpart[(size_t)(ks * B_SZ + b) * N_TOK + n0 + t];
      lsh[t] = ls;
    }
  }
  __syncthreads();

  // gate stage 2 (folds 0.8): gsh = 0.8*sigmoid(cg2 @ hl + cg2_b)
  if (t < C_DIM) {
    float z = cg2_b[t];
#pragma unroll
    for (int j = 0; j < BOT; ++j) z += cg2_w[t * BOT + j] * hl[j];
    gsh[t] = 0.8f / (1.f + __expf(-z));
  }
  __syncthreads();

  // phase 2: out = x + gsh*(W_w @ y)/l ; c-range per wave (W reads scalar)
  const int n = t & 63, cg = t >> 6;
  float y[I_DIM];
#pragma unroll
  for (int i = 0; i < I_DIM; ++i) y[i] = Ysh[n][i];
  const float inv = 1.0f / lsh[n];
  const float* xb = x + ((size_t)b * C_DIM + cg * 16) * N_TOK + n0 + n;
  float* ob = out + ((size_t)b * C_DIM + cg * 16) * N_TOK + n0 + n;
#pragma unroll
  for (int c16 = 0; c16 < 16; ++c16) {
    const int c = cg * 16 + c16;
    float sacc = 0.f;
#pragma unroll
    for (int i = 0; i < I_DIM; ++i) sacc += W_w[c * I_DIM + i] * y[i];
    ob[(size_t)c16 * N_TOK] = xb[(size_t)c16 * N_TOK] + gsh[c] * inv * sacc;
  }
}

extern "C" void kernel_launch(void* const* d_in, const int* in_sizes, int n_in,
                              void* d_out, int out_size, void* d_ws, size_t ws_size,
                              hipStream_t stream) {
  const float* x = (const float*)d_in[0];
  const float* g_w = (const float*)d_in[1];
  const float* theta_w = (const float*)d_in[2];
  const float* phi_w = (const float*)d_in[3];
  const float* W_w = (const float*)d_in[4];
  const float* cg1_w = (const float*)d_in[5];
  const float* cg1_b = (const float*)d_in[6];
  const float* cg2_w = (const float*)d_in[7];
  const float* cg2_b = (const float*)d_in[8];
  float* out = (float*)d_out;

  char* w = (char*)d_ws;
  const size_t bfsz = (size_t)B_SZ * N_TOK * I_DIM * sizeof(unsigned short);
  unsigned short* Qb = (unsigned short*)(w);
  unsigned short* Kb = (unsigned short*)(w + bfsz);
  unsigned short* VT = (unsigned short*)(w + 2 * bfsz);
  float* pooled = (float*)(w + 3 * bfsz);
  char* w2 = w + 3 * bfsz + 8192;

  int KS = 16;
  {
    // per split: Ypart bf16 (B*N*32*2) + Lpart f32 (B*N*4)
    const size_t per = (size_t)B_SZ * N_TOK * (I_DIM * 2 + 4);
    while (KS > 1 && (3 * bfsz + 8192 + (size_t)KS * per) > ws_size) KS >>= 1;
  }
  float* Lpart = (float*)w2;
  unsigned short* Ypart =
      (unsigned short*)(w2 + (size_t)KS * B_SZ * N_TOK * sizeof(float));
  int tps = N_TILES / KS;

  proj_pool_kernel<<<dim3(344), 256, 0, stream>>>(x, g_w, theta_w, phi_w, Qb,
                                                  Kb, VT, pooled);
  attn_kernel<<<dim3(72, KS, B_SZ), 256, 0, stream>>>(Qb, Kb, VT, Ypart, Lpart, tps);
  epilogue_kernel<<<dim3(N_TOK / 64, B_SZ), 256, 0, stream>>>(
      x, W_w, pooled, cg1_w, cg1_b, cg2_w, cg2_b, Ypart, Lpart, out, KS);
}